// Round 2
// baseline (280.204 us; speedup 1.0000x reference)
//
#include <hip/hip_runtime.h>
#include <hip/hip_bf16.h>

// Problem constants (from reference)
constexpr int T_ = 4;
constexpr int B_ = 8;
constexpr int N_ = 5000;
constexpr int E_ = 80000;
constexpr int TBN = T_ * B_ * N_;   // 160000

// ---------------------------------------------------------------------------
// CSR build kernels (edges shared across all T*B graphs)
// ---------------------------------------------------------------------------
__global__ void k_degree(const int* __restrict__ dst, int* __restrict__ deg) {
    int e = blockIdx.x * 256 + threadIdx.x;
    if (e < E_) atomicAdd(&deg[dst[e]], 1);
}

// single-block exclusive scan over deg[0..N) -> row_start[0..N]
__global__ void k_scan(const int* __restrict__ deg, int* __restrict__ row_start) {
    __shared__ int sums[256];
    const int tid = threadIdx.x;
    const int per = 20;                    // 256*20 = 5120 >= N
    const int base = tid * per;
    int local = 0;
    for (int i = 0; i < per; ++i) {
        int idx = base + i;
        if (idx < N_) local += deg[idx];
    }
    sums[tid] = local;
    __syncthreads();
    for (int off = 1; off < 256; off <<= 1) {
        int v = 0;
        if (tid >= off) v = sums[tid - off];
        __syncthreads();
        if (tid >= off) sums[tid] += v;
        __syncthreads();
    }
    int running = sums[tid] - local;       // exclusive prefix
    for (int i = 0; i < per; ++i) {
        int idx = base + i;
        if (idx < N_) {
            row_start[idx] = running;
            running += deg[idx];
        }
    }
    if (tid == 255) row_start[N_] = sums[255];
}

__global__ void k_scatter(const int* __restrict__ src, const int* __restrict__ dst,
                          const int* __restrict__ row_start, int* __restrict__ cursor,
                          int* __restrict__ csr_src) {
    int e = blockIdx.x * 256 + threadIdx.x;
    if (e < E_) {
        int d = dst[e];
        int pos = atomicAdd(&cursor[d], 1);
        csr_src[row_start[d] + pos] = src[e];
    }
}

// ---------------------------------------------------------------------------
// Init: h0 = relu(charge * W_embed); gs0 = h0 @ W1s[0]; vec = v
// ---------------------------------------------------------------------------
__global__ void k_init(const float* __restrict__ vs, const float* __restrict__ charges,
                       const float* __restrict__ W_embed, const float* __restrict__ W1,
                       float* __restrict__ h, float* __restrict__ gs,
                       float* __restrict__ vec) {
    __shared__ float s_we[16];
    __shared__ float s_W1s[256];
    const int tid = threadIdx.x;
    if (tid < 16) s_we[tid] = W_embed[tid];
    s_W1s[tid] = W1[tid];                  // layer 0, rows 0..15
    __syncthreads();

    int g = blockIdx.x * 256 + tid;        // exact: 625*256 == TBN
    int tb = g / N_;
    int n  = g - tb * N_;
    int b  = tb % B_;
    float c = charges[b * N_ + n];

    float hv[16];
#pragma unroll
    for (int f = 0; f < 16; ++f) hv[f] = fmaxf(c * s_we[f], 0.0f);

    float gsv[16];
#pragma unroll
    for (int f = 0; f < 16; ++f) gsv[f] = 0.0f;
#pragma unroll
    for (int j = 0; j < 16; ++j) {
        float hj = hv[j];
#pragma unroll
        for (int f = 0; f < 16; ++f) gsv[f] += hj * s_W1s[j * 16 + f];
    }

    float4* hp = (float4*)(h + (size_t)g * 16);
    float4* gp = (float4*)(gs + (size_t)g * 16);
#pragma unroll
    for (int q = 0; q < 4; ++q) {
        hp[q] = make_float4(hv[q*4], hv[q*4+1], hv[q*4+2], hv[q*4+3]);
        gp[q] = make_float4(gsv[q*4], gsv[q*4+1], gsv[q*4+2], gsv[q*4+3]);
    }
    vec[g*3+0] = vs[g*3+0];
    vec[g*3+1] = vs[g*3+1];
    vec[g*3+2] = vs[g*3+2];
}

// ---------------------------------------------------------------------------
// Fused layer kernel. Reads gs_in (layer-l src projections, written by the
// PREVIOUS kernel only — no intra-kernel races), writes gs_out (layer l+1).
// gd is recomputed thread-locally from h[g]; h/vec are own-index only.
// ---------------------------------------------------------------------------
template <int LYR, bool HAS_NEXT>
__global__ void k_layer(const float* __restrict__ xs, const float* __restrict__ W1,
                        const float* __restrict__ b1, const float* __restrict__ W2,
                        const float* __restrict__ b2, const float* __restrict__ Wv,
                        const int* __restrict__ row_start, const int* __restrict__ csr_src,
                        float* __restrict__ h, const float* __restrict__ gs_in,
                        float* __restrict__ gs_out, float* __restrict__ vec) {
    __shared__ float s_w1e[16], s_wv[16], s_b2[16], s_b1[16];
    __shared__ float s_W1d[256];           // current layer, rows 16..31
    __shared__ float s_W2[256];
    __shared__ float s_W1sn[256];          // next layer, rows 0..15
    const int tid = threadIdx.x;
    if (tid < 16) {
        s_w1e[tid] = W1[LYR * 528 + 512 + tid];
        s_wv[tid]  = Wv[LYR * 16 + tid];
        s_b2[tid]  = b2[LYR * 16 + tid];
        s_b1[tid]  = b1[LYR * 16 + tid];
    }
    s_W1d[tid] = W1[LYR * 528 + 256 + tid];
    s_W2[tid]  = W2[LYR * 256 + tid];
    if (HAS_NEXT) s_W1sn[tid] = W1[(LYR + 1) * 528 + tid];
    __syncthreads();

    int g = blockIdx.x * 256 + tid;
    int tb = g / N_;
    int n  = g - tb * N_;
    size_t nb = (size_t)tb * N_;

    float xn0 = xs[(size_t)g*3+0], xn1 = xs[(size_t)g*3+1], xn2 = xs[(size_t)g*3+2];

    // h[g] (own index only)
    float hn[16];
    {
        const float4* p = (const float4*)(h + (size_t)g * 16);
        float4 q0 = p[0], q1 = p[1], q2 = p[2], q3 = p[3];
        hn[0]=q0.x; hn[1]=q0.y; hn[2]=q0.z; hn[3]=q0.w;
        hn[4]=q1.x; hn[5]=q1.y; hn[6]=q1.z; hn[7]=q1.w;
        hn[8]=q2.x; hn[9]=q2.y; hn[10]=q2.z; hn[11]=q2.w;
        hn[12]=q3.x; hn[13]=q3.y; hn[14]=q3.z; hn[15]=q3.w;
    }

    // gd = h[g] @ W1d + b1  (thread-local recompute)
    float gdn[16];
#pragma unroll
    for (int f = 0; f < 16; ++f) gdn[f] = s_b1[f];
#pragma unroll
    for (int j = 0; j < 16; ++j) {
        float hj = hn[j];
#pragma unroll
        for (int f = 0; f < 16; ++f) gdn[f] += hj * s_W1d[j * 16 + f];
    }

    float agg[16];
#pragma unroll
    for (int f = 0; f < 16; ++f) agg[f] = 0.0f;
    float av0 = 0.0f, av1 = 0.0f, av2 = 0.0f;

    const int rs = row_start[n];
    const int re = row_start[n + 1];
    for (int e = rs; e < re; ++e) {
        int s = csr_src[e];
        size_t si = nb + (size_t)s;
        float d0 = xn0 - xs[si*3+0];
        float d1 = xn1 - xs[si*3+1];
        float d2v = xn2 - xs[si*3+2];
        float dd = d0*d0 + d1*d1 + d2v*d2v;

        const float4* p = (const float4*)(gs_in + si * 16);
        float4 q0 = p[0], q1 = p[1], q2 = p[2], q3 = p[3];
        float gsv[16] = {q0.x,q0.y,q0.z,q0.w, q1.x,q1.y,q1.z,q1.w,
                         q2.x,q2.y,q2.z,q2.w, q3.x,q3.y,q3.z,q3.w};

        float sval = 0.0f;
#pragma unroll
        for (int f = 0; f < 16; ++f) {
            float mv = gsv[f] + gdn[f] + dd * s_w1e[f];
            mv = fmaxf(mv, 0.0f);
            agg[f] += mv;
            sval += mv * s_wv[f];
        }
        av0 += d0 * sval;
        av1 += d1 * sval;
        av2 += d2v * sval;
    }

    // h update: h += relu(agg @ W2 + b2)
    float hnew[16];
#pragma unroll
    for (int f = 0; f < 16; ++f) hnew[f] = s_b2[f];
#pragma unroll
    for (int j = 0; j < 16; ++j) {
        float aj = agg[j];
#pragma unroll
        for (int f = 0; f < 16; ++f) hnew[f] += aj * s_W2[j * 16 + f];
    }
#pragma unroll
    for (int f = 0; f < 16; ++f) hnew[f] = hn[f] + fmaxf(hnew[f], 0.0f);

    vec[(size_t)g*3+0] += av0;
    vec[(size_t)g*3+1] += av1;
    vec[(size_t)g*3+2] += av2;

    {
        float4* hp = (float4*)(h + (size_t)g * 16);
#pragma unroll
        for (int q = 0; q < 4; ++q)
            hp[q] = make_float4(hnew[q*4], hnew[q*4+1], hnew[q*4+2], hnew[q*4+3]);
    }

    if (HAS_NEXT) {
        float gsv[16];
#pragma unroll
        for (int f = 0; f < 16; ++f) gsv[f] = 0.0f;
#pragma unroll
        for (int j = 0; j < 16; ++j) {
            float hj = hnew[j];
#pragma unroll
            for (int f = 0; f < 16; ++f) gsv[f] += hj * s_W1sn[j * 16 + f];
        }
        float4* gp = (float4*)(gs_out + (size_t)g * 16);
#pragma unroll
        for (int q = 0; q < 4; ++q)
            gp[q] = make_float4(gsv[q*4], gsv[q*4+1], gsv[q*4+2], gsv[q*4+3]);
    }
}

// ---------------------------------------------------------------------------
// Final: out[b*N+n] = sum_t softmax(theta)[t] * (vec[t,b,n] + xs[t,b,n])
// ---------------------------------------------------------------------------
__global__ void k_final(const float* __restrict__ xs, const float* __restrict__ vec,
                        const float* __restrict__ theta, float* __restrict__ out) {
    int g = blockIdx.x * 256 + threadIdx.x;
    if (g >= B_ * N_) return;
    float t0 = theta[0], t1 = theta[1], t2 = theta[2], t3 = theta[3];
    float mx = fmaxf(fmaxf(t0, t1), fmaxf(t2, t3));
    float e0 = expf(t0 - mx), e1 = expf(t1 - mx), e2 = expf(t2 - mx), e3 = expf(t3 - mx);
    float inv = 1.0f / (e0 + e1 + e2 + e3);
    float w[4] = {e0 * inv, e1 * inv, e2 * inv, e3 * inv};

    int b = g / N_;
    int n = g - b * N_;
    float o0 = 0.0f, o1 = 0.0f, o2 = 0.0f;
#pragma unroll
    for (int t = 0; t < 4; ++t) {
        size_t idx = ((size_t)(t * B_ + b) * N_ + n) * 3;
        o0 += w[t] * (vec[idx+0] + xs[idx+0]);
        o1 += w[t] * (vec[idx+1] + xs[idx+1]);
        o2 += w[t] * (vec[idx+2] + xs[idx+2]);
    }
    out[(size_t)g*3+0] = o0;
    out[(size_t)g*3+1] = o1;
    out[(size_t)g*3+2] = o2;
}

// ---------------------------------------------------------------------------
extern "C" void kernel_launch(void* const* d_in, const int* in_sizes, int n_in,
                              void* d_out, int out_size, void* d_ws, size_t ws_size,
                              hipStream_t stream) {
    const float* xs       = (const float*)d_in[0];
    const float* vs       = (const float*)d_in[1];
    const float* charges  = (const float*)d_in[2];
    const int*   edge_src = (const int*)d_in[3];
    const int*   edge_dst = (const int*)d_in[4];
    const float* theta    = (const float*)d_in[5];
    const float* W_embed  = (const float*)d_in[6];
    const float* W1       = (const float*)d_in[7];
    const float* b1       = (const float*)d_in[8];
    const float* W2       = (const float*)d_in[9];
    const float* b2       = (const float*)d_in[10];
    const float* Wv       = (const float*)d_in[11];
    float* out = (float*)d_out;

    // workspace layout (256B aligned)
    char* w = (char*)d_ws;
    size_t off = 0;
    auto take = [&](size_t bytes) {
        size_t o = off;
        off = (off + bytes + 255) & ~(size_t)255;
        return o;
    };
    int*   deg       = (int*)(w + take((size_t)N_ * 4));
    int*   cursor    = (int*)(w + take((size_t)N_ * 4));
    int*   row_start = (int*)(w + take((size_t)(N_ + 1) * 4));
    int*   csr_src   = (int*)(w + take((size_t)E_ * 4));
    float* h         = (float*)(w + take((size_t)TBN * 16 * 4));
    float* gs0       = (float*)(w + take((size_t)TBN * 16 * 4));
    float* gs1       = (float*)(w + take((size_t)TBN * 16 * 4));
    float* vec       = (float*)(w + take((size_t)TBN * 3 * 4));
    (void)ws_size;

    hipMemsetAsync(deg, 0, (size_t)N_ * 4, stream);
    hipMemsetAsync(cursor, 0, (size_t)N_ * 4, stream);

    const int eb = (E_ + 255) / 256;        // 313
    k_degree<<<eb, 256, 0, stream>>>(edge_dst, deg);
    k_scan<<<1, 256, 0, stream>>>(deg, row_start);
    k_scatter<<<eb, 256, 0, stream>>>(edge_src, edge_dst, row_start, cursor, csr_src);

    const int nb = TBN / 256;               // 625 exact
    k_init<<<nb, 256, 0, stream>>>(vs, charges, W_embed, W1, h, gs0, vec);
    // ping-pong gs buffers: layer l reads gs_in, writes next-layer gs_out
    k_layer<0, true ><<<nb, 256, 0, stream>>>(xs, W1, b1, W2, b2, Wv, row_start, csr_src, h, gs0, gs1, vec);
    k_layer<1, true ><<<nb, 256, 0, stream>>>(xs, W1, b1, W2, b2, Wv, row_start, csr_src, h, gs1, gs0, vec);
    k_layer<2, false><<<nb, 256, 0, stream>>>(xs, W1, b1, W2, b2, Wv, row_start, csr_src, h, gs0, nullptr, vec);

    const int fb = (B_ * N_ + 255) / 256;   // 157
    k_final<<<fb, 256, 0, stream>>>(xs, vec, theta, out);
}

// Round 3
// 264.197 us; speedup vs baseline: 1.0606x; 1.0606x over previous
//
#include <hip/hip_runtime.h>
#include <hip/hip_bf16.h>

// Problem constants (from reference)
constexpr int T_ = 4;
constexpr int B_ = 8;
constexpr int N_ = 5000;
constexpr int E_ = 80000;
constexpr int TBN = T_ * B_ * N_;   // 160000
constexpr int CHUNKS = 20;          // 20*256 = 5120 >= N_ nodes per graph
constexpr int NXCD = 8;

// ---------------------------------------------------------------------------
// CSR build kernels (edges shared across all T*B graphs)
// ---------------------------------------------------------------------------
__global__ void k_degree(const int* __restrict__ dst, int* __restrict__ deg) {
    int e = blockIdx.x * 256 + threadIdx.x;
    if (e < E_) atomicAdd(&deg[dst[e]], 1);
}

// single-block exclusive scan over deg[0..N) -> row_start[0..N]
__global__ void k_scan(const int* __restrict__ deg, int* __restrict__ row_start) {
    __shared__ int sums[256];
    const int tid = threadIdx.x;
    const int per = 20;                    // 256*20 = 5120 >= N
    const int base = tid * per;
    int local = 0;
    for (int i = 0; i < per; ++i) {
        int idx = base + i;
        if (idx < N_) local += deg[idx];
    }
    sums[tid] = local;
    __syncthreads();
    for (int off = 1; off < 256; off <<= 1) {
        int v = 0;
        if (tid >= off) v = sums[tid - off];
        __syncthreads();
        if (tid >= off) sums[tid] += v;
        __syncthreads();
    }
    int running = sums[tid] - local;       // exclusive prefix
    for (int i = 0; i < per; ++i) {
        int idx = base + i;
        if (idx < N_) {
            row_start[idx] = running;
            running += deg[idx];
        }
    }
    if (tid == 255) row_start[N_] = sums[255];
}

__global__ void k_scatter(const int* __restrict__ src, const int* __restrict__ dst,
                          const int* __restrict__ row_start, int* __restrict__ cursor,
                          int* __restrict__ csr_src) {
    int e = blockIdx.x * 256 + threadIdx.x;
    if (e < E_) {
        int d = dst[e];
        int pos = atomicAdd(&cursor[d], 1);
        csr_src[row_start[d] + pos] = src[e];
    }
}

// ---------------------------------------------------------------------------
// Init: h0 = relu(charge * W_embed); gs0 = h0 @ W1s[0]; vec = v
// ---------------------------------------------------------------------------
__global__ void k_init(const float* __restrict__ vs, const float* __restrict__ charges,
                       const float* __restrict__ W_embed, const float* __restrict__ W1,
                       float* __restrict__ h, float* __restrict__ gs,
                       float* __restrict__ vec) {
    __shared__ float s_we[16];
    __shared__ float s_W1s[256];
    const int tid = threadIdx.x;
    if (tid < 16) s_we[tid] = W_embed[tid];
    s_W1s[tid] = W1[tid];                  // layer 0, rows 0..15
    __syncthreads();

    int g = blockIdx.x * 256 + tid;        // exact: 625*256 == TBN
    int tb = g / N_;
    int n  = g - tb * N_;
    int b  = tb % B_;
    float c = charges[b * N_ + n];

    float hv[16];
#pragma unroll
    for (int f = 0; f < 16; ++f) hv[f] = fmaxf(c * s_we[f], 0.0f);

    float gsv[16];
#pragma unroll
    for (int f = 0; f < 16; ++f) gsv[f] = 0.0f;
#pragma unroll
    for (int j = 0; j < 16; ++j) {
        float hj = hv[j];
#pragma unroll
        for (int f = 0; f < 16; ++f) gsv[f] += hj * s_W1s[j * 16 + f];
    }

    float4* hp = (float4*)(h + (size_t)g * 16);
    float4* gp = (float4*)(gs + (size_t)g * 16);
#pragma unroll
    for (int q = 0; q < 4; ++q) {
        hp[q] = make_float4(hv[q*4], hv[q*4+1], hv[q*4+2], hv[q*4+3]);
        gp[q] = make_float4(gsv[q*4], gsv[q*4+1], gsv[q*4+2], gsv[q*4+3]);
    }
    vec[g*3+0] = vs[g*3+0];
    vec[g*3+1] = vs[g*3+1];
    vec[g*3+2] = vs[g*3+2];
}

// ---------------------------------------------------------------------------
// Fused layer kernel, XCD-swizzled: all chunks of graph tb land on XCD tb%8
// (blockIdx round-robins across XCDs). Per-XCD working set = 4 graphs
// (~1.5 MB) -> gs/xs gathers hit in the XCD's 4 MB L2.
// Reads gs_in (written by previous kernel only), writes gs_out (next layer).
// ---------------------------------------------------------------------------
template <int LYR, bool HAS_NEXT>
__global__ void k_layer(const float* __restrict__ xs, const float* __restrict__ W1,
                        const float* __restrict__ b1, const float* __restrict__ W2,
                        const float* __restrict__ b2, const float* __restrict__ Wv,
                        const int* __restrict__ row_start, const int* __restrict__ csr_src,
                        float* __restrict__ h, const float* __restrict__ gs_in,
                        float* __restrict__ gs_out, float* __restrict__ vec) {
    __shared__ float s_w1e[16], s_wv[16], s_b2[16], s_b1[16];
    __shared__ float s_W1d[256];           // current layer, rows 16..31
    __shared__ float s_W2[256];
    __shared__ float s_W1sn[256];          // next layer, rows 0..15
    const int tid = threadIdx.x;
    if (tid < 16) {
        s_w1e[tid] = W1[LYR * 528 + 512 + tid];
        s_wv[tid]  = Wv[LYR * 16 + tid];
        s_b2[tid]  = b2[LYR * 16 + tid];
        s_b1[tid]  = b1[LYR * 16 + tid];
    }
    s_W1d[tid] = W1[LYR * 528 + 256 + tid];
    s_W2[tid]  = W2[LYR * 256 + tid];
    if (HAS_NEXT) s_W1sn[tid] = W1[(LYR + 1) * 528 + tid];
    __syncthreads();

    // XCD-aware swizzle: bid % 8 is the XCD (round-robin dispatch).
    // Bijection over 640 blocks -> (tb, chunk) in 32 x 20, with tb % 8 == xcd.
    const int bid   = blockIdx.x;
    const int xcd   = bid & 7;
    const int j     = bid >> 3;            // 0..79
    const int tb    = xcd + NXCD * (j / CHUNKS);
    const int chunk = j % CHUNKS;
    const int n     = chunk * 256 + tid;
    if (n >= N_) return;                   // no syncs below

    const int g = tb * N_ + n;
    const size_t nb = (size_t)tb * N_;

    float xn0 = xs[(size_t)g*3+0], xn1 = xs[(size_t)g*3+1], xn2 = xs[(size_t)g*3+2];

    // h[g] (own index only)
    float hn[16];
    {
        const float4* p = (const float4*)(h + (size_t)g * 16);
        float4 q0 = p[0], q1 = p[1], q2 = p[2], q3 = p[3];
        hn[0]=q0.x; hn[1]=q0.y; hn[2]=q0.z; hn[3]=q0.w;
        hn[4]=q1.x; hn[5]=q1.y; hn[6]=q1.z; hn[7]=q1.w;
        hn[8]=q2.x; hn[9]=q2.y; hn[10]=q2.z; hn[11]=q2.w;
        hn[12]=q3.x; hn[13]=q3.y; hn[14]=q3.z; hn[15]=q3.w;
    }

    // gd = h[g] @ W1d + b1  (thread-local recompute)
    float gdn[16];
#pragma unroll
    for (int f = 0; f < 16; ++f) gdn[f] = s_b1[f];
#pragma unroll
    for (int jj = 0; jj < 16; ++jj) {
        float hj = hn[jj];
#pragma unroll
        for (int f = 0; f < 16; ++f) gdn[f] += hj * s_W1d[jj * 16 + f];
    }

    float agg[16];
#pragma unroll
    for (int f = 0; f < 16; ++f) agg[f] = 0.0f;
    float av0 = 0.0f, av1 = 0.0f, av2 = 0.0f;

    const int rs = row_start[n];
    const int re = row_start[n + 1];
#pragma unroll 2
    for (int e = rs; e < re; ++e) {
        int s = csr_src[e];
        size_t si = nb + (size_t)s;
        float d0 = xn0 - xs[si*3+0];
        float d1 = xn1 - xs[si*3+1];
        float d2v = xn2 - xs[si*3+2];
        float dd = d0*d0 + d1*d1 + d2v*d2v;

        const float4* p = (const float4*)(gs_in + si * 16);
        float4 q0 = p[0], q1 = p[1], q2 = p[2], q3 = p[3];
        float gsv[16] = {q0.x,q0.y,q0.z,q0.w, q1.x,q1.y,q1.z,q1.w,
                         q2.x,q2.y,q2.z,q2.w, q3.x,q3.y,q3.z,q3.w};

        float sval = 0.0f;
#pragma unroll
        for (int f = 0; f < 16; ++f) {
            float mv = gsv[f] + gdn[f] + dd * s_w1e[f];
            mv = fmaxf(mv, 0.0f);
            agg[f] += mv;
            sval += mv * s_wv[f];
        }
        av0 += d0 * sval;
        av1 += d1 * sval;
        av2 += d2v * sval;
    }

    // h update: h += relu(agg @ W2 + b2)
    float hnew[16];
#pragma unroll
    for (int f = 0; f < 16; ++f) hnew[f] = s_b2[f];
#pragma unroll
    for (int jj = 0; jj < 16; ++jj) {
        float aj = agg[jj];
#pragma unroll
        for (int f = 0; f < 16; ++f) hnew[f] += aj * s_W2[jj * 16 + f];
    }
#pragma unroll
    for (int f = 0; f < 16; ++f) hnew[f] = hn[f] + fmaxf(hnew[f], 0.0f);

    vec[(size_t)g*3+0] += av0;
    vec[(size_t)g*3+1] += av1;
    vec[(size_t)g*3+2] += av2;

    {
        float4* hp = (float4*)(h + (size_t)g * 16);
#pragma unroll
        for (int q = 0; q < 4; ++q)
            hp[q] = make_float4(hnew[q*4], hnew[q*4+1], hnew[q*4+2], hnew[q*4+3]);
    }

    if (HAS_NEXT) {
        float gsv[16];
#pragma unroll
        for (int f = 0; f < 16; ++f) gsv[f] = 0.0f;
#pragma unroll
        for (int jj = 0; jj < 16; ++jj) {
            float hj = hnew[jj];
#pragma unroll
            for (int f = 0; f < 16; ++f) gsv[f] += hj * s_W1sn[jj * 16 + f];
        }
        float4* gp = (float4*)(gs_out + (size_t)g * 16);
#pragma unroll
        for (int q = 0; q < 4; ++q)
            gp[q] = make_float4(gsv[q*4], gsv[q*4+1], gsv[q*4+2], gsv[q*4+3]);
    }
}

// ---------------------------------------------------------------------------
// Final: out[b*N+n] = sum_t softmax(theta)[t] * (vec[t,b,n] + xs[t,b,n])
// ---------------------------------------------------------------------------
__global__ void k_final(const float* __restrict__ xs, const float* __restrict__ vec,
                        const float* __restrict__ theta, float* __restrict__ out) {
    int g = blockIdx.x * 256 + threadIdx.x;
    if (g >= B_ * N_) return;
    float t0 = theta[0], t1 = theta[1], t2 = theta[2], t3 = theta[3];
    float mx = fmaxf(fmaxf(t0, t1), fmaxf(t2, t3));
    float e0 = expf(t0 - mx), e1 = expf(t1 - mx), e2 = expf(t2 - mx), e3 = expf(t3 - mx);
    float inv = 1.0f / (e0 + e1 + e2 + e3);
    float w[4] = {e0 * inv, e1 * inv, e2 * inv, e3 * inv};

    int b = g / N_;
    int n = g - b * N_;
    float o0 = 0.0f, o1 = 0.0f, o2 = 0.0f;
#pragma unroll
    for (int t = 0; t < 4; ++t) {
        size_t idx = ((size_t)(t * B_ + b) * N_ + n) * 3;
        o0 += w[t] * (vec[idx+0] + xs[idx+0]);
        o1 += w[t] * (vec[idx+1] + xs[idx+1]);
        o2 += w[t] * (vec[idx+2] + xs[idx+2]);
    }
    out[(size_t)g*3+0] = o0;
    out[(size_t)g*3+1] = o1;
    out[(size_t)g*3+2] = o2;
}

// ---------------------------------------------------------------------------
extern "C" void kernel_launch(void* const* d_in, const int* in_sizes, int n_in,
                              void* d_out, int out_size, void* d_ws, size_t ws_size,
                              hipStream_t stream) {
    const float* xs       = (const float*)d_in[0];
    const float* vs       = (const float*)d_in[1];
    const float* charges  = (const float*)d_in[2];
    const int*   edge_src = (const int*)d_in[3];
    const int*   edge_dst = (const int*)d_in[4];
    const float* theta    = (const float*)d_in[5];
    const float* W_embed  = (const float*)d_in[6];
    const float* W1       = (const float*)d_in[7];
    const float* b1       = (const float*)d_in[8];
    const float* W2       = (const float*)d_in[9];
    const float* b2       = (const float*)d_in[10];
    const float* Wv       = (const float*)d_in[11];
    float* out = (float*)d_out;

    // workspace layout (256B aligned)
    char* w = (char*)d_ws;
    size_t off = 0;
    auto take = [&](size_t bytes) {
        size_t o = off;
        off = (off + bytes + 255) & ~(size_t)255;
        return o;
    };
    int*   deg       = (int*)(w + take((size_t)N_ * 4));
    int*   cursor    = (int*)(w + take((size_t)N_ * 4));
    int*   row_start = (int*)(w + take((size_t)(N_ + 1) * 4));
    int*   csr_src   = (int*)(w + take((size_t)E_ * 4));
    float* h         = (float*)(w + take((size_t)TBN * 16 * 4));
    float* gs0       = (float*)(w + take((size_t)TBN * 16 * 4));
    float* gs1       = (float*)(w + take((size_t)TBN * 16 * 4));
    float* vec       = (float*)(w + take((size_t)TBN * 3 * 4));
    (void)ws_size;

    hipMemsetAsync(deg, 0, (size_t)N_ * 4, stream);
    hipMemsetAsync(cursor, 0, (size_t)N_ * 4, stream);

    const int eb = (E_ + 255) / 256;        // 313
    k_degree<<<eb, 256, 0, stream>>>(edge_dst, deg);
    k_scan<<<1, 256, 0, stream>>>(deg, row_start);
    k_scatter<<<eb, 256, 0, stream>>>(edge_src, edge_dst, row_start, cursor, csr_src);

    const int nb = TBN / 256;               // 625 exact
    k_init<<<nb, 256, 0, stream>>>(vs, charges, W_embed, W1, h, gs0, vec);

    const int lb = 32 * CHUNKS;             // 640 swizzled blocks
    k_layer<0, true ><<<lb, 256, 0, stream>>>(xs, W1, b1, W2, b2, Wv, row_start, csr_src, h, gs0, gs1, vec);
    k_layer<1, true ><<<lb, 256, 0, stream>>>(xs, W1, b1, W2, b2, Wv, row_start, csr_src, h, gs1, gs0, vec);
    k_layer<2, false><<<lb, 256, 0, stream>>>(xs, W1, b1, W2, b2, Wv, row_start, csr_src, h, gs0, nullptr, vec);

    const int fb = (B_ * N_ + 255) / 256;   // 157
    k_final<<<fb, 256, 0, stream>>>(xs, vec, theta, out);
}

// Round 4
// 182.635 us; speedup vs baseline: 1.5342x; 1.4466x over previous
//
#include <hip/hip_runtime.h>
#include <hip/hip_bf16.h>

// Problem constants (from reference)
constexpr int T_ = 4;
constexpr int B_ = 8;
constexpr int N_ = 5000;
constexpr int E_ = 80000;
constexpr int TBN = T_ * B_ * N_;   // 160000
constexpr int NXCD = 8;

// layer-kernel geometry: 4 lanes per node, 64 nodes per 256-thread block
constexpr int NPB = 64;                       // nodes per block
constexpr int CH  = (N_ + NPB - 1) / NPB;     // 79 chunks per graph
constexpr int GRP = T_ * B_ / NXCD;           // 4 graphs per XCD
constexpr int LB  = NXCD * CH * GRP;          // 2528 blocks

// ---------------------------------------------------------------------------
// CSR build kernels (edges shared across all T*B graphs)
// ---------------------------------------------------------------------------
__global__ void k_degree(const int* __restrict__ dst, int* __restrict__ deg) {
    int e = blockIdx.x * 256 + threadIdx.x;
    if (e < E_) atomicAdd(&deg[dst[e]], 1);
}

__global__ void k_scan(const int* __restrict__ deg, int* __restrict__ row_start) {
    __shared__ int sums[256];
    const int tid = threadIdx.x;
    const int per = 20;                    // 256*20 = 5120 >= N
    const int base = tid * per;
    int local = 0;
    for (int i = 0; i < per; ++i) {
        int idx = base + i;
        if (idx < N_) local += deg[idx];
    }
    sums[tid] = local;
    __syncthreads();
    for (int off = 1; off < 256; off <<= 1) {
        int v = 0;
        if (tid >= off) v = sums[tid - off];
        __syncthreads();
        if (tid >= off) sums[tid] += v;
        __syncthreads();
    }
    int running = sums[tid] - local;       // exclusive prefix
    for (int i = 0; i < per; ++i) {
        int idx = base + i;
        if (idx < N_) {
            row_start[idx] = running;
            running += deg[idx];
        }
    }
    if (tid == 255) row_start[N_] = sums[255];
}

__global__ void k_scatter(const int* __restrict__ src, const int* __restrict__ dst,
                          const int* __restrict__ row_start, int* __restrict__ cursor,
                          int* __restrict__ csr_src) {
    int e = blockIdx.x * 256 + threadIdx.x;
    if (e < E_) {
        int d = dst[e];
        int pos = atomicAdd(&cursor[d], 1);
        csr_src[row_start[d] + pos] = src[e];
    }
}

// ---------------------------------------------------------------------------
// xs4 build: one float4 per node for single-load position gathers
// ---------------------------------------------------------------------------
__global__ void k_init(const float* __restrict__ xs, float4* __restrict__ xs4) {
    int g = blockIdx.x * 256 + threadIdx.x;   // 625*256 == TBN exact
    xs4[g] = make_float4(xs[3*g], xs[3*g+1], xs[3*g+2], 0.0f);
}

// ---------------------------------------------------------------------------
// Fused layer kernel. 4 lanes per node, edges striped across the quad.
// LYR==0: gs0[s] = c_s * P, gd0 = c_n * Q + b1 (relu(c*we)=c*relu(we), c>=0);
//         reads only charges (4B gather) — no h/gs_in; writes vec = vs + av.
// LYR>=1: gathers gs_in (64B) + xs4 (16B); gd recomputed from own h.
// !HAS_NEXT: skips agg/h-update/gs_out entirely (h dead after last layer).
// XCD swizzle: graph tb lands on XCD tb%8 (blockIdx round-robins XCDs).
// ---------------------------------------------------------------------------
template <int LYR, bool HAS_NEXT>
__global__ __launch_bounds__(256) void k_layer(
        const float4* __restrict__ xs4, const float* __restrict__ charges,
        const float* __restrict__ vs, const float* __restrict__ W_embed,
        const float* __restrict__ W1, const float* __restrict__ b1,
        const float* __restrict__ W2, const float* __restrict__ b2,
        const float* __restrict__ Wv,
        const int* __restrict__ row_start, const int* __restrict__ csr_src,
        float* __restrict__ h, const float* __restrict__ gs_in,
        float* __restrict__ gs_out, float* __restrict__ vec) {
    __shared__ float s_w1e[16], s_wv[16], s_b2[16], s_b1[16];
    __shared__ float s_W1d[256];           // current layer, rows 16..31
    __shared__ float s_W2[256];
    __shared__ float s_W1sn[256];          // next layer, rows 0..15
    __shared__ float s_P[16], s_Q[16], s_rwe[16];   // layer-0 collapse
    const int tid = threadIdx.x;
    if (tid < 16) {
        s_w1e[tid] = W1[LYR * 528 + 512 + tid];
        s_wv[tid]  = Wv[LYR * 16 + tid];
        s_b2[tid]  = b2[LYR * 16 + tid];
        s_b1[tid]  = b1[LYR * 16 + tid];
    }
    s_W1d[tid] = W1[LYR * 528 + 256 + tid];
    s_W2[tid]  = W2[LYR * 256 + tid];
    if (HAS_NEXT) s_W1sn[tid] = W1[(LYR + 1) * 528 + tid];
    __syncthreads();
    if (LYR == 0) {
        if (tid < 16) {
            float accP = 0.0f, accQ = 0.0f;
            for (int j = 0; j < 16; ++j) {
                float r = fmaxf(W_embed[j], 0.0f);
                accP += r * W1[j * 16 + tid];          // W1s layer0
                accQ += r * s_W1d[j * 16 + tid];       // W1d layer0
            }
            s_P[tid] = accP; s_Q[tid] = accQ;
            s_rwe[tid] = fmaxf(W_embed[tid], 0.0f);
        }
        __syncthreads();
    }

    // XCD swizzle bijection over 2528 = 8 * 316 blocks
    const int bid   = blockIdx.x;
    const int xcd   = bid & 7;
    const int j     = bid >> 3;            // 0..315
    const int tb    = xcd + NXCD * (j / CH);
    const int chunk = j % CH;
    const int node  = chunk * NPB + (tid >> 2);
    const int q     = tid & 3;
    if (node >= N_) return;                // whole quad exits together; no syncs below

    const int g = tb * N_ + node;
    const size_t nb = (size_t)tb * N_;
    const float* cb = charges + (tb % B_) * N_;

    const float4 xn = xs4[g];

    // gd = h[g] @ W1d + b1 (thread-local; duplicated across quad)
    float hn[16];
    float gdn[16];
    if (LYR == 0) {
        const float c = cb[node];
#pragma unroll
        for (int f = 0; f < 16; ++f) {
            hn[f]  = c * s_rwe[f];
            gdn[f] = c * s_Q[f] + s_b1[f];
        }
    } else {
        const float4* p = (const float4*)(h + (size_t)g * 16);
        float4 q0 = p[0], q1 = p[1], q2 = p[2], q3 = p[3];
        hn[0]=q0.x; hn[1]=q0.y; hn[2]=q0.z; hn[3]=q0.w;
        hn[4]=q1.x; hn[5]=q1.y; hn[6]=q1.z; hn[7]=q1.w;
        hn[8]=q2.x; hn[9]=q2.y; hn[10]=q2.z; hn[11]=q2.w;
        hn[12]=q3.x; hn[13]=q3.y; hn[14]=q3.z; hn[15]=q3.w;
#pragma unroll
        for (int f = 0; f < 16; ++f) gdn[f] = s_b1[f];
#pragma unroll
        for (int jj = 0; jj < 16; ++jj) {
            float hj = hn[jj];
#pragma unroll
            for (int f = 0; f < 16; ++f) gdn[f] += hj * s_W1d[jj * 16 + f];
        }
    }

    float agg[16];
#pragma unroll
    for (int f = 0; f < 16; ++f) agg[f] = 0.0f;
    float av0 = 0.0f, av1 = 0.0f, av2 = 0.0f;

    const int rs = row_start[node];
    const int re = row_start[node + 1];
#pragma unroll 2
    for (int e = rs + q; e < re; e += 4) {     // edges striped across the quad
        int s = csr_src[e];
        size_t si = nb + (size_t)s;
        float4 xsrc = xs4[si];
        float d0 = xn.x - xsrc.x;
        float d1 = xn.y - xsrc.y;
        float d2v = xn.z - xsrc.z;
        float dd = d0*d0 + d1*d1 + d2v*d2v;

        float gsv[16];
        if (LYR == 0) {
            float cs = cb[s];
#pragma unroll
            for (int f = 0; f < 16; ++f) gsv[f] = cs * s_P[f];
        } else {
            const float4* p = (const float4*)(gs_in + si * 16);
            float4 q0 = p[0], q1 = p[1], q2 = p[2], q3 = p[3];
            gsv[0]=q0.x; gsv[1]=q0.y; gsv[2]=q0.z; gsv[3]=q0.w;
            gsv[4]=q1.x; gsv[5]=q1.y; gsv[6]=q1.z; gsv[7]=q1.w;
            gsv[8]=q2.x; gsv[9]=q2.y; gsv[10]=q2.z; gsv[11]=q2.w;
            gsv[12]=q3.x; gsv[13]=q3.y; gsv[14]=q3.z; gsv[15]=q3.w;
        }

        float sval = 0.0f;
#pragma unroll
        for (int f = 0; f < 16; ++f) {
            float mv = gsv[f] + gdn[f] + dd * s_w1e[f];
            mv = fmaxf(mv, 0.0f);
            if (HAS_NEXT) agg[f] += mv;
            sval += mv * s_wv[f];
        }
        av0 += d0 * sval;
        av1 += d1 * sval;
        av2 += d2v * sval;
    }

    // quad reduce (lanes of a quad are consecutive & quad-aligned)
    av0 += __shfl_xor(av0, 1); av0 += __shfl_xor(av0, 2);
    av1 += __shfl_xor(av1, 1); av1 += __shfl_xor(av1, 2);
    av2 += __shfl_xor(av2, 1); av2 += __shfl_xor(av2, 2);

    if (q < 3) {
        float myav = (q == 0) ? av0 : ((q == 1) ? av1 : av2);
        size_t vi = (size_t)g * 3 + q;
        float base = (LYR == 0) ? vs[vi] : vec[vi];
        vec[vi] = base + myav;
    }

    if (HAS_NEXT) {
#pragma unroll
        for (int f = 0; f < 16; ++f) {
            agg[f] += __shfl_xor(agg[f], 1);
            agg[f] += __shfl_xor(agg[f], 2);
        }
        // h update: hnew = hn + relu(agg @ W2 + b2)  (full width per lane)
        float hnew[16];
#pragma unroll
        for (int f = 0; f < 16; ++f) hnew[f] = s_b2[f];
#pragma unroll
        for (int jj = 0; jj < 16; ++jj) {
            float aj = agg[jj];
#pragma unroll
            for (int f = 0; f < 16; ++f) hnew[f] += aj * s_W2[jj * 16 + f];
        }
#pragma unroll
        for (int f = 0; f < 16; ++f) hnew[f] = hn[f] + fmaxf(hnew[f], 0.0f);

        // this lane stores its quarter of h and of gs_out
        ((float4*)(h + (size_t)g * 16))[q] =
            make_float4(hnew[q*4], hnew[q*4+1], hnew[q*4+2], hnew[q*4+3]);

        float gso[4] = {0.0f, 0.0f, 0.0f, 0.0f};
#pragma unroll
        for (int jj = 0; jj < 16; ++jj) {
            float hj = hnew[jj];
#pragma unroll
            for (int k = 0; k < 4; ++k) gso[k] += hj * s_W1sn[jj * 16 + q * 4 + k];
        }
        ((float4*)(gs_out + (size_t)g * 16))[q] =
            make_float4(gso[0], gso[1], gso[2], gso[3]);
    }
}

// ---------------------------------------------------------------------------
// Final: out[b*N+n] = sum_t softmax(theta)[t] * (vec[t,b,n] + xs[t,b,n])
// ---------------------------------------------------------------------------
__global__ void k_final(const float* __restrict__ xs, const float* __restrict__ vec,
                        const float* __restrict__ theta, float* __restrict__ out) {
    int g = blockIdx.x * 256 + threadIdx.x;
    if (g >= B_ * N_) return;
    float t0 = theta[0], t1 = theta[1], t2 = theta[2], t3 = theta[3];
    float mx = fmaxf(fmaxf(t0, t1), fmaxf(t2, t3));
    float e0 = expf(t0 - mx), e1 = expf(t1 - mx), e2 = expf(t2 - mx), e3 = expf(t3 - mx);
    float inv = 1.0f / (e0 + e1 + e2 + e3);
    float w[4] = {e0 * inv, e1 * inv, e2 * inv, e3 * inv};

    int b = g / N_;
    int n = g - b * N_;
    float o0 = 0.0f, o1 = 0.0f, o2 = 0.0f;
#pragma unroll
    for (int t = 0; t < 4; ++t) {
        size_t idx = ((size_t)(t * B_ + b) * N_ + n) * 3;
        o0 += w[t] * (vec[idx+0] + xs[idx+0]);
        o1 += w[t] * (vec[idx+1] + xs[idx+1]);
        o2 += w[t] * (vec[idx+2] + xs[idx+2]);
    }
    out[(size_t)g*3+0] = o0;
    out[(size_t)g*3+1] = o1;
    out[(size_t)g*3+2] = o2;
}

// ---------------------------------------------------------------------------
extern "C" void kernel_launch(void* const* d_in, const int* in_sizes, int n_in,
                              void* d_out, int out_size, void* d_ws, size_t ws_size,
                              hipStream_t stream) {
    const float* xs       = (const float*)d_in[0];
    const float* vs       = (const float*)d_in[1];
    const float* charges  = (const float*)d_in[2];
    const int*   edge_src = (const int*)d_in[3];
    const int*   edge_dst = (const int*)d_in[4];
    const float* theta    = (const float*)d_in[5];
    const float* W_embed  = (const float*)d_in[6];
    const float* W1       = (const float*)d_in[7];
    const float* b1       = (const float*)d_in[8];
    const float* W2       = (const float*)d_in[9];
    const float* b2       = (const float*)d_in[10];
    const float* Wv       = (const float*)d_in[11];
    float* out = (float*)d_out;

    // workspace layout (256B aligned)
    char* w = (char*)d_ws;
    size_t off = 0;
    auto take = [&](size_t bytes) {
        size_t o = off;
        off = (off + bytes + 255) & ~(size_t)255;
        return o;
    };
    int*    deg       = (int*)(w + take((size_t)N_ * 4));
    int*    cursor    = (int*)(w + take((size_t)N_ * 4));
    int*    row_start = (int*)(w + take((size_t)(N_ + 1) * 4));
    int*    csr_src   = (int*)(w + take((size_t)E_ * 4));
    float*  h         = (float*)(w + take((size_t)TBN * 16 * 4));
    float*  gsA       = (float*)(w + take((size_t)TBN * 16 * 4));
    float*  gsB       = (float*)(w + take((size_t)TBN * 16 * 4));
    float*  vec       = (float*)(w + take((size_t)TBN * 3 * 4));
    float4* xs4       = (float4*)(w + take((size_t)TBN * 16));
    (void)ws_size;

    hipMemsetAsync(deg, 0, (size_t)N_ * 4, stream);
    hipMemsetAsync(cursor, 0, (size_t)N_ * 4, stream);

    const int eb = (E_ + 255) / 256;        // 313
    k_degree<<<eb, 256, 0, stream>>>(edge_dst, deg);
    k_scan<<<1, 256, 0, stream>>>(deg, row_start);
    k_scatter<<<eb, 256, 0, stream>>>(edge_src, edge_dst, row_start, cursor, csr_src);

    k_init<<<TBN / 256, 256, 0, stream>>>(xs, xs4);

    // layer 0 writes gsA (for layer 1); layer 1 reads gsA, writes gsB; layer 2 reads gsB
    k_layer<0, true ><<<LB, 256, 0, stream>>>(xs4, charges, vs, W_embed, W1, b1, W2, b2, Wv,
                                              row_start, csr_src, h, nullptr, gsA, vec);
    k_layer<1, true ><<<LB, 256, 0, stream>>>(xs4, charges, vs, W_embed, W1, b1, W2, b2, Wv,
                                              row_start, csr_src, h, gsA, gsB, vec);
    k_layer<2, false><<<LB, 256, 0, stream>>>(xs4, charges, vs, W_embed, W1, b1, W2, b2, Wv,
                                              row_start, csr_src, h, gsB, nullptr, vec);

    const int fb = (B_ * N_ + 255) / 256;   // 157
    k_final<<<fb, 256, 0, stream>>>(xs, vec, theta, out);
}

// Round 5
// 124.570 us; speedup vs baseline: 2.2494x; 1.4661x over previous
//
#include <hip/hip_runtime.h>
#include <hip/hip_bf16.h>

// Problem constants (from reference)
constexpr int T_ = 4;
constexpr int B_ = 8;
constexpr int N_ = 5000;
constexpr int E_ = 80000;
constexpr int TBN = T_ * B_ * N_;   // 160000
constexpr int NXCD = 8;

// layer-kernel geometry: 4 lanes per node, 64 nodes per 256-thread block
constexpr int NPB = 64;                       // nodes per block
constexpr int CH  = (N_ + NPB - 1) / NPB;     // 79 chunks per graph
constexpr int GRP = T_ * B_ / NXCD;           // 4 graphs per XCD
constexpr int LB  = NXCD * CH * GRP;          // 2528 blocks

// bf16 pack/unpack (round-to-nearest-ish via +0x8000)
__device__ __forceinline__ unsigned bf16pack2(float lo, float hi) {
    unsigned ul = (__float_as_uint(lo) + 0x8000u) >> 16;
    unsigned uh = (__float_as_uint(hi) + 0x8000u) & 0xffff0000u;
    return uh | ul;
}
__device__ __forceinline__ void bf16unpack2(unsigned u, float& lo, float& hi) {
    lo = __uint_as_float(u << 16);
    hi = __uint_as_float(u & 0xffff0000u);
}

// ---------------------------------------------------------------------------
// CSR build kernels (edges shared across all T*B graphs)
// ---------------------------------------------------------------------------
__global__ void k_degree(const int* __restrict__ dst, int* __restrict__ deg) {
    int e = blockIdx.x * 256 + threadIdx.x;
    if (e < E_) atomicAdd(&deg[dst[e]], 1);
}

__global__ void k_scan(const int* __restrict__ deg, int* __restrict__ row_start) {
    __shared__ int sums[256];
    const int tid = threadIdx.x;
    const int per = 20;                    // 256*20 = 5120 >= N
    const int base = tid * per;
    int local = 0;
    for (int i = 0; i < per; ++i) {
        int idx = base + i;
        if (idx < N_) local += deg[idx];
    }
    sums[tid] = local;
    __syncthreads();
    for (int off = 1; off < 256; off <<= 1) {
        int v = 0;
        if (tid >= off) v = sums[tid - off];
        __syncthreads();
        if (tid >= off) sums[tid] += v;
        __syncthreads();
    }
    int running = sums[tid] - local;       // exclusive prefix
    for (int i = 0; i < per; ++i) {
        int idx = base + i;
        if (idx < N_) {
            row_start[idx] = running;
            running += deg[idx];
        }
    }
    if (tid == 255) row_start[N_] = sums[255];
}

__global__ void k_scatter(const int* __restrict__ src, const int* __restrict__ dst,
                          const int* __restrict__ row_start, int* __restrict__ cursor,
                          int* __restrict__ csr_src) {
    int e = blockIdx.x * 256 + threadIdx.x;
    if (e < E_) {
        int d = dst[e];
        int pos = atomicAdd(&cursor[d], 1);
        csr_src[row_start[d] + pos] = src[e];
    }
}

// ---------------------------------------------------------------------------
// xs4 build
// ---------------------------------------------------------------------------
__global__ void k_init(const float* __restrict__ xs, float4* __restrict__ xs4) {
    int g = blockIdx.x * 256 + threadIdx.x;   // 625*256 == TBN exact
    xs4[g] = make_float4(xs[3*g], xs[3*g+1], xs[3*g+2], 0.0f);
}

// ---------------------------------------------------------------------------
// Fused layer kernel. 4 lanes/node, edges striped across quad, depth-2
// software-pipelined gathers. State layout:
//   h  : fp32 [TBN][16]  (own-index; lane stores/loads its float4 quarter)
//   gs : bf16 [TBN][16] = 2 x uint4 per node (gathered per edge)
//   gd : bf16 [TBN][16]  (own-index full load; written quarter per lane;
//                         PRECOMPUTED by previous layer's tail — includes b1)
// LYR==0: gs0[s]=c_s*P, gd0=c_n*Q+b1 inline (relu(c*we)=c*relu(we), c>=0);
//         per-edge gather is charges (4B). vec = vs + av (overwrite).
// HAS_NEXT tail (feature-split across quad): agg butterfly -> hnew quarter ->
//         hfull via 16 shfl -> gs_next/gd_next quarters -> stores.
// ---------------------------------------------------------------------------
template <int LYR, bool HAS_NEXT>
__global__ __launch_bounds__(256, 4) void k_layer(
        const float4* __restrict__ xs4, const float* __restrict__ charges,
        const float* __restrict__ vs, const float* __restrict__ W_embed,
        const float* __restrict__ W1, const float* __restrict__ b1,
        const float* __restrict__ W2, const float* __restrict__ b2,
        const float* __restrict__ Wv,
        const int* __restrict__ row_start, const int* __restrict__ csr_src,
        float* __restrict__ h, const uint4* __restrict__ gs_in,
        uint2* __restrict__ gs_out, unsigned* __restrict__ gd,
        float* __restrict__ vec) {
    __shared__ float s_w1e[16], s_wv[16], s_b2[16], s_b1[16], s_b1n[16];
    __shared__ float s_W2[256];
    __shared__ float s_W1sn[256];          // next layer rows 0..15
    __shared__ float s_W1dn[256];          // next layer rows 16..31
    __shared__ float s_P[16], s_Q[16], s_rwe[16];   // layer-0 collapse
    const int tid = threadIdx.x;
    if (tid < 16) {
        s_w1e[tid] = W1[LYR * 528 + 512 + tid];
        s_wv[tid]  = Wv[LYR * 16 + tid];
        s_b2[tid]  = b2[LYR * 16 + tid];
        s_b1[tid]  = b1[LYR * 16 + tid];
        if (HAS_NEXT) s_b1n[tid] = b1[(LYR + 1) * 16 + tid];
    }
    s_W2[tid] = W2[LYR * 256 + tid];
    if (HAS_NEXT) {
        s_W1sn[tid] = W1[(LYR + 1) * 528 + tid];
        s_W1dn[tid] = W1[(LYR + 1) * 528 + 256 + tid];
    }
    if (LYR == 0 && tid < 16) {
        float accP = 0.0f, accQ = 0.0f;
        for (int j = 0; j < 16; ++j) {
            float r = fmaxf(W_embed[j], 0.0f);
            accP += r * W1[j * 16 + tid];          // W1s layer0
            accQ += r * W1[256 + j * 16 + tid];    // W1d layer0
        }
        s_P[tid] = accP; s_Q[tid] = accQ;
        s_rwe[tid] = fmaxf(W_embed[tid], 0.0f);
    }
    __syncthreads();

    // XCD swizzle bijection over 2528 = 8 * 316 blocks
    const int bid   = blockIdx.x;
    const int xcd   = bid & 7;
    const int j     = bid >> 3;            // 0..315
    const int tb    = xcd + NXCD * (j / CH);
    const int chunk = j % CH;
    const int node  = chunk * NPB + (tid >> 2);
    const int q     = tid & 3;
    if (node >= N_) return;                // whole quad exits together; no syncs below

    const int g = tb * N_ + node;
    const size_t nb = (size_t)tb * N_;
    const float* cb = charges + (tb % B_) * N_;

    const float4 xn = xs4[g];

    // gdn: full 16, per lane
    float gdn[16];
    float c0 = 0.0f;
    if (LYR == 0) {
        c0 = cb[node];
#pragma unroll
        for (int f = 0; f < 16; ++f) gdn[f] = c0 * s_Q[f] + s_b1[f];
    } else {
        const uint4* gdp = (const uint4*)gd + (size_t)g * 2;
        uint4 da = gdp[0], db = gdp[1];
        bf16unpack2(da.x, gdn[0], gdn[1]);  bf16unpack2(da.y, gdn[2], gdn[3]);
        bf16unpack2(da.z, gdn[4], gdn[5]);  bf16unpack2(da.w, gdn[6], gdn[7]);
        bf16unpack2(db.x, gdn[8], gdn[9]);  bf16unpack2(db.y, gdn[10], gdn[11]);
        bf16unpack2(db.z, gdn[12], gdn[13]); bf16unpack2(db.w, gdn[14], gdn[15]);
    }

    float agg[16];
#pragma unroll
    for (int f = 0; f < 16; ++f) agg[f] = 0.0f;
    float av0 = 0.0f, av1 = 0.0f, av2 = 0.0f;

    const int rs = row_start[node];
    const int re = row_start[node + 1];

    // depth-2 software-pipelined edge loop (edges striped across quad)
    int e = rs + q;
    bool have = e < re;
    int s = have ? csr_src[e] : 0;
    size_t si = nb + (size_t)s;
    float4 xc = xs4[si];
    float  cs = 0.0f;
    uint4  ga, gb;
    if (LYR == 0) cs = cb[s];
    else { ga = gs_in[si * 2]; gb = gs_in[si * 2 + 1]; }

    while (have) {
        // issue next edge's gathers
        int e2 = e + 4;
        bool have2 = e2 < re;
        int s2 = have2 ? csr_src[e2] : 0;
        size_t si2 = nb + (size_t)s2;
        float4 xc2 = xs4[si2];
        float  cs2 = 0.0f;
        uint4  ga2, gb2;
        if (LYR == 0) cs2 = cb[s2];
        else { ga2 = gs_in[si2 * 2]; gb2 = gs_in[si2 * 2 + 1]; }

        // compute current edge
        float d0 = xn.x - xc.x;
        float d1 = xn.y - xc.y;
        float d2v = xn.z - xc.z;
        float dd = d0*d0 + d1*d1 + d2v*d2v;

        float gsf[16];
        if (LYR == 0) {
#pragma unroll
            for (int f = 0; f < 16; ++f) gsf[f] = cs * s_P[f];
        } else {
            bf16unpack2(ga.x, gsf[0], gsf[1]);  bf16unpack2(ga.y, gsf[2], gsf[3]);
            bf16unpack2(ga.z, gsf[4], gsf[5]);  bf16unpack2(ga.w, gsf[6], gsf[7]);
            bf16unpack2(gb.x, gsf[8], gsf[9]);  bf16unpack2(gb.y, gsf[10], gsf[11]);
            bf16unpack2(gb.z, gsf[12], gsf[13]); bf16unpack2(gb.w, gsf[14], gsf[15]);
        }

        float sval = 0.0f;
#pragma unroll
        for (int f = 0; f < 16; ++f) {
            float mv = fmaxf(__builtin_fmaf(dd, s_w1e[f], gdn[f]) + gsf[f], 0.0f);
            if (HAS_NEXT) agg[f] += mv;
            sval = __builtin_fmaf(mv, s_wv[f], sval);
        }
        av0 = __builtin_fmaf(d0, sval, av0);
        av1 = __builtin_fmaf(d1, sval, av1);
        av2 = __builtin_fmaf(d2v, sval, av2);

        e = e2; have = have2; xc = xc2; cs = cs2; ga = ga2; gb = gb2;
    }

    // quad reduce of av (lanes of a quad are consecutive & quad-aligned)
    av0 += __shfl_xor(av0, 1); av0 += __shfl_xor(av0, 2);
    av1 += __shfl_xor(av1, 1); av1 += __shfl_xor(av1, 2);
    av2 += __shfl_xor(av2, 1); av2 += __shfl_xor(av2, 2);

    if (q < 3) {
        float myav = (q == 0) ? av0 : ((q == 1) ? av1 : av2);
        size_t vi = (size_t)g * 3 + q;
        float base = (LYR == 0) ? vs[vi] : vec[vi];
        vec[vi] = base + myav;
    }

    if (HAS_NEXT) {
        // full agg across quad (hnew needs all 16 j)
#pragma unroll
        for (int f = 0; f < 16; ++f) {
            agg[f] += __shfl_xor(agg[f], 1);
            agg[f] += __shfl_xor(agg[f], 2);
        }

        // hn quarter for this lane
        float hq[4];
        if (LYR == 0) {
#pragma unroll
            for (int k = 0; k < 4; ++k) hq[k] = c0 * s_rwe[q * 4 + k];
        } else {
            float4 hv = ((const float4*)h)[(size_t)g * 4 + q];
            hq[0] = hv.x; hq[1] = hv.y; hq[2] = hv.z; hq[3] = hv.w;
        }

        // hnew quarter: hq += relu(agg @ W2 + b2) for own 4 features
        float acc[4];
#pragma unroll
        for (int k = 0; k < 4; ++k) acc[k] = s_b2[q * 4 + k];
#pragma unroll
        for (int jj = 0; jj < 16; ++jj) {
            float aj = agg[jj];
#pragma unroll
            for (int k = 0; k < 4; ++k)
                acc[k] = __builtin_fmaf(aj, s_W2[jj * 16 + q * 4 + k], acc[k]);
        }
#pragma unroll
        for (int k = 0; k < 4; ++k) hq[k] += fmaxf(acc[k], 0.0f);

        // exchange quarters -> full hnew
        const int lane = tid & 63;
        const int lbase = lane & ~3;
        float hfull[16];
#pragma unroll
        for (int sq = 0; sq < 4; ++sq) {
#pragma unroll
            for (int k = 0; k < 4; ++k)
                hfull[sq * 4 + k] = __shfl(hq[k], lbase + sq, 64);
        }

        // next-layer projections, own 4 columns
        float gso[4], gdo[4];
#pragma unroll
        for (int k = 0; k < 4; ++k) { gso[k] = 0.0f; gdo[k] = s_b1n[q * 4 + k]; }
#pragma unroll
        for (int jj = 0; jj < 16; ++jj) {
            float hj = hfull[jj];
#pragma unroll
            for (int k = 0; k < 4; ++k) {
                gso[k] = __builtin_fmaf(hj, s_W1sn[jj * 16 + q * 4 + k], gso[k]);
                gdo[k] = __builtin_fmaf(hj, s_W1dn[jj * 16 + q * 4 + k], gdo[k]);
            }
        }

        ((float4*)h)[(size_t)g * 4 + q] = make_float4(hq[0], hq[1], hq[2], hq[3]);
        gs_out[(size_t)g * 4 + q] = make_uint2(bf16pack2(gso[0], gso[1]),
                                               bf16pack2(gso[2], gso[3]));
        ((uint2*)gd)[(size_t)g * 4 + q] = make_uint2(bf16pack2(gdo[0], gdo[1]),
                                                     bf16pack2(gdo[2], gdo[3]));
    }
}

// ---------------------------------------------------------------------------
// Final: out[b*N+n] = sum_t softmax(theta)[t] * (vec[t,b,n] + xs[t,b,n])
// ---------------------------------------------------------------------------
__global__ void k_final(const float* __restrict__ xs, const float* __restrict__ vec,
                        const float* __restrict__ theta, float* __restrict__ out) {
    int g = blockIdx.x * 256 + threadIdx.x;
    if (g >= B_ * N_) return;
    float t0 = theta[0], t1 = theta[1], t2 = theta[2], t3 = theta[3];
    float mx = fmaxf(fmaxf(t0, t1), fmaxf(t2, t3));
    float e0 = expf(t0 - mx), e1 = expf(t1 - mx), e2 = expf(t2 - mx), e3 = expf(t3 - mx);
    float inv = 1.0f / (e0 + e1 + e2 + e3);
    float w[4] = {e0 * inv, e1 * inv, e2 * inv, e3 * inv};

    int b = g / N_;
    int n = g - b * N_;
    float o0 = 0.0f, o1 = 0.0f, o2 = 0.0f;
#pragma unroll
    for (int t = 0; t < 4; ++t) {
        size_t idx = ((size_t)(t * B_ + b) * N_ + n) * 3;
        o0 += w[t] * (vec[idx+0] + xs[idx+0]);
        o1 += w[t] * (vec[idx+1] + xs[idx+1]);
        o2 += w[t] * (vec[idx+2] + xs[idx+2]);
    }
    out[(size_t)g*3+0] = o0;
    out[(size_t)g*3+1] = o1;
    out[(size_t)g*3+2] = o2;
}

// ---------------------------------------------------------------------------
extern "C" void kernel_launch(void* const* d_in, const int* in_sizes, int n_in,
                              void* d_out, int out_size, void* d_ws, size_t ws_size,
                              hipStream_t stream) {
    const float* xs       = (const float*)d_in[0];
    const float* vs       = (const float*)d_in[1];
    const float* charges  = (const float*)d_in[2];
    const int*   edge_src = (const int*)d_in[3];
    const int*   edge_dst = (const int*)d_in[4];
    const float* theta    = (const float*)d_in[5];
    const float* W_embed  = (const float*)d_in[6];
    const float* W1       = (const float*)d_in[7];
    const float* b1       = (const float*)d_in[8];
    const float* W2       = (const float*)d_in[9];
    const float* b2       = (const float*)d_in[10];
    const float* Wv       = (const float*)d_in[11];
    float* out = (float*)d_out;

    // workspace layout (256B aligned)
    char* w = (char*)d_ws;
    size_t off = 0;
    auto take = [&](size_t bytes) {
        size_t o = off;
        off = (off + bytes + 255) & ~(size_t)255;
        return o;
    };
    int*      deg       = (int*)(w + take((size_t)N_ * 4));
    int*      cursor    = (int*)(w + take((size_t)N_ * 4));
    int*      row_start = (int*)(w + take((size_t)(N_ + 1) * 4));
    int*      csr_src   = (int*)(w + take((size_t)E_ * 4));
    float*    h         = (float*)(w + take((size_t)TBN * 16 * 4));
    unsigned* gsA       = (unsigned*)(w + take((size_t)TBN * 32));   // bf16 x16
    unsigned* gsB       = (unsigned*)(w + take((size_t)TBN * 32));
    unsigned* gd        = (unsigned*)(w + take((size_t)TBN * 32));
    float*    vec       = (float*)(w + take((size_t)TBN * 3 * 4));
    float4*   xs4       = (float4*)(w + take((size_t)TBN * 16));
    (void)ws_size;

    hipMemsetAsync(deg, 0, (size_t)N_ * 4, stream);
    hipMemsetAsync(cursor, 0, (size_t)N_ * 4, stream);

    const int eb = (E_ + 255) / 256;        // 313
    k_degree<<<eb, 256, 0, stream>>>(edge_dst, deg);
    k_scan<<<1, 256, 0, stream>>>(deg, row_start);
    k_scatter<<<eb, 256, 0, stream>>>(edge_src, edge_dst, row_start, cursor, csr_src);

    k_init<<<TBN / 256, 256, 0, stream>>>(xs, xs4);

    // layer 0 writes gsA+gd (for layer 1); layer 1 reads gsA, writes gsB+gd;
    // layer 2 reads gsB+gd, writes nothing but vec
    k_layer<0, true ><<<LB, 256, 0, stream>>>(xs4, charges, vs, W_embed, W1, b1, W2, b2, Wv,
                                              row_start, csr_src, h, nullptr,
                                              (uint2*)gsA, gd, vec);
    k_layer<1, true ><<<LB, 256, 0, stream>>>(xs4, charges, vs, W_embed, W1, b1, W2, b2, Wv,
                                              row_start, csr_src, h, (const uint4*)gsA,
                                              (uint2*)gsB, gd, vec);
    k_layer<2, false><<<LB, 256, 0, stream>>>(xs4, charges, vs, W_embed, W1, b1, W2, b2, Wv,
                                              row_start, csr_src, h, (const uint4*)gsB,
                                              nullptr, gd, vec);

    const int fb = (B_ * N_ + 255) / 256;   // 157
    k_final<<<fb, 256, 0, stream>>>(xs, vec, theta, out);
}